// Round 3
// baseline (1113.702 us; speedup 1.0000x reference)
//
#include <hip/hip_runtime.h>

// Conv2d NCHW, stride=1, pad=1, N=16, C=8, K=8, H=W=1024, 3x3, fp32.
// Round 3: float4 loads (low VALU overhead) + explicit VGPR budget
// (__launch_bounds__(256,4) -> 128 VGPR cap) + manual 2-stage software
// pipeline over ci with statically-named buffers (inA/inB), so next-ci
// loads overlap current-ci FMAs instead of serializing.

#define R 2
#define HH 1024
#define WW 1024
#define CI 8
#define CO 8

__global__ __launch_bounds__(256, 4) void conv3x3_kernel(
    const float* __restrict__ x,      // [16][8][1024][1024]
    const float* __restrict__ wgt,    // [8][8][3][3]
    const float* __restrict__ bias,   // [8]
    float* __restrict__ out)          // [16][8][1024][1024]
{
    const int w0 = threadIdx.x * 4;            // 0..1020, 16B aligned
    const int h0 = blockIdx.x * R;             // 0..1022
    const int n  = blockIdx.y;                 // 0..15

    const long HW = (long)HH * WW;
    const float* xn = x + (long)n * CI * HW;

    float acc[CO][R][4];
#pragma unroll
    for (int co = 0; co < CO; ++co) {
        const float b = bias[co];              // uniform -> s_load
#pragma unroll
        for (int r = 0; r < R; ++r)
#pragma unroll
            for (int p = 0; p < 4; ++p) acc[co][r][p] = b;
    }

    // ---- helpers (static array names only; rule #20) ----
    auto load_rows = [&](float (&in)[R + 2][6], int ci) {
#pragma unroll
        for (int r = 0; r < R + 2; ++r) {
            const int h = h0 - 1 + r;
            const bool hv = (h >= 0) && (h < HH);     // block-uniform
            const float* row = xn + (long)ci * HW + (long)h * WW;
            float4 mid;
            float left, right;
            if (hv) {
                mid   = *reinterpret_cast<const float4*>(row + w0);
                left  = (w0 > 0)      ? row[w0 - 1] : 0.0f;
                right = (w0 + 4 < WW) ? row[w0 + 4] : 0.0f;
            } else {
                mid = make_float4(0.f, 0.f, 0.f, 0.f);
                left = 0.f; right = 0.f;
            }
            in[r][0] = left;
            in[r][1] = mid.x; in[r][2] = mid.y; in[r][3] = mid.z; in[r][4] = mid.w;
            in[r][5] = right;
        }
    };

    auto do_fma = [&](float (&in)[R + 2][6], int ci) {
#pragma unroll
        for (int co = 0; co < CO; ++co) {
            const float* wp = wgt + ((co * CI + ci) * 9);
            float wv[9];
#pragma unroll
            for (int k = 0; k < 9; ++k) wv[k] = wp[k];   // uniform -> SGPR
#pragma unroll
            for (int r = 0; r < R; ++r)
#pragma unroll
                for (int kh = 0; kh < 3; ++kh)
#pragma unroll
                    for (int kw = 0; kw < 3; ++kw)
#pragma unroll
                        for (int p = 0; p < 4; ++p)
                            acc[co][r][p] = fmaf(in[r + kh][p + kw],
                                                 wv[kh * 3 + kw], acc[co][r][p]);
        }
    };

    // ---- 2-stage pipeline over ci (CI=8, step 2) ----
    float inA[R + 2][6], inB[R + 2][6];
    load_rows(inA, 0);                          // prologue
    for (int ci = 0; ci < CI; ci += 2) {        // 4 iterations, uniform
        load_rows(inB, ci + 1);                 // prefetch odd
        do_fma(inA, ci);                        // compute even
        const int cn = (ci + 2 < CI) ? (ci + 2) : (CI - 1);  // clamp (redundant ok)
        load_rows(inA, cn);                     // prefetch next even
        do_fma(inB, ci + 1);                    // compute odd
    }

    // Stores: one float4 per (co, r).
#pragma unroll
    for (int co = 0; co < CO; ++co) {
        float* op = out + ((long)n * CO + co) * HW + (long)h0 * WW + w0;
#pragma unroll
        for (int r = 0; r < R; ++r) {
            float4 v = make_float4(acc[co][r][0], acc[co][r][1],
                                   acc[co][r][2], acc[co][r][3]);
            *reinterpret_cast<float4*>(op + (long)r * WW) = v;
        }
    }
}

extern "C" void kernel_launch(void* const* d_in, const int* in_sizes, int n_in,
                              void* d_out, int out_size, void* d_ws, size_t ws_size,
                              hipStream_t stream) {
    const float* x    = (const float*)d_in[0];
    const float* wgt  = (const float*)d_in[1];
    const float* bias = (const float*)d_in[2];
    float* out = (float*)d_out;

    dim3 grid(HH / R, 16, 1);   // (512, 16)
    dim3 block(256, 1, 1);
    conv3x3_kernel<<<grid, block, 0, stream>>>(x, wgt, bias, out);
}

// Round 4
// 634.507 us; speedup vs baseline: 1.7552x; 1.7552x over previous
//
#include <hip/hip_runtime.h>

// Conv2d NCHW, stride=1, pad=1, N=16, C=8, K=8, H=W=1024, 3x3, fp32.
// Round 4: co-split. Block = (256,2) threads; threadIdx.y picks co half
// (0-3 or 4-7) over the SAME spatial tile -> per-thread acc halves to 32
// VGPRs, allocator has slack, both halves share x lines via L1.
// float4 row loads + 2 edge scalars per row per ci. Weights wave-uniform.

#define R 2
#define HH 1024
#define WW 1024
#define CI 8
#define CO_T 4     // output channels per thread

__global__ __launch_bounds__(512) void conv3x3_kernel(
    const float* __restrict__ x,      // [16][8][1024][1024]
    const float* __restrict__ wgt,    // [8][8][3][3]
    const float* __restrict__ bias,   // [8]
    float* __restrict__ out)          // [16][8][1024][1024]
{
    const int w0  = threadIdx.x * 4;           // 0..1020, 16B aligned
    const int cob = threadIdx.y * CO_T;        // 0 or 4 (wave-uniform)
    const int h0  = blockIdx.x * R;            // 0..1022
    const int n   = blockIdx.y;                // 0..15

    const long HW = (long)HH * WW;
    const float* xn = x + (long)n * CI * HW;

    float acc[CO_T][R][4];
#pragma unroll
    for (int co = 0; co < CO_T; ++co) {
        const float b = bias[cob + co];        // uniform -> s_load
#pragma unroll
        for (int r = 0; r < R; ++r)
#pragma unroll
            for (int p = 0; p < 4; ++p) acc[co][r][p] = b;
    }

    for (int ci = 0; ci < CI; ++ci) {          // uniform runtime loop
        const float* xc = xn + (long)ci * HW;

        // Stage R+2 input rows, 6 floats each: [w0-1 .. w0+4], zero-padded.
        float in[R + 2][6];
#pragma unroll
        for (int r = 0; r < R + 2; ++r) {
            const int h = h0 - 1 + r;
            const bool hv = (h >= 0) && (h < HH);   // block-uniform
            const float* row = xc + (long)h * WW;
            float4 mid;
            float left, right;
            if (hv) {
                mid   = *reinterpret_cast<const float4*>(row + w0);
                left  = (w0 > 0)      ? row[w0 - 1] : 0.0f;
                right = (w0 + 4 < WW) ? row[w0 + 4] : 0.0f;
            } else {
                mid = make_float4(0.f, 0.f, 0.f, 0.f);
                left = 0.f; right = 0.f;
            }
            in[r][0] = left;
            in[r][1] = mid.x; in[r][2] = mid.y; in[r][3] = mid.z; in[r][4] = mid.w;
            in[r][5] = right;
        }

        // 4 co x R rows x 4 w x 9 taps.
#pragma unroll
        for (int co = 0; co < CO_T; ++co) {
            const float* wp = wgt + (((cob + co) * CI + ci) * 9);
            float wv[9];
#pragma unroll
            for (int k = 0; k < 9; ++k) wv[k] = wp[k];   // uniform -> SGPR
#pragma unroll
            for (int r = 0; r < R; ++r)
#pragma unroll
                for (int kh = 0; kh < 3; ++kh)
#pragma unroll
                    for (int kw = 0; kw < 3; ++kw)
#pragma unroll
                        for (int p = 0; p < 4; ++p)
                            acc[co][r][p] = fmaf(in[r + kh][p + kw],
                                                 wv[kh * 3 + kw], acc[co][r][p]);
        }
    }

    // Stores: one float4 per (co, r).
#pragma unroll
    for (int co = 0; co < CO_T; ++co) {
        float* op = out + ((long)n * CI + (cob + co)) * HW + (long)h0 * WW + w0;
#pragma unroll
        for (int r = 0; r < R; ++r) {
            float4 v = make_float4(acc[co][r][0], acc[co][r][1],
                                   acc[co][r][2], acc[co][r][3]);
            *reinterpret_cast<float4*>(op + (long)r * WW) = v;
        }
    }
}

extern "C" void kernel_launch(void* const* d_in, const int* in_sizes, int n_in,
                              void* d_out, int out_size, void* d_ws, size_t ws_size,
                              hipStream_t stream) {
    const float* x    = (const float*)d_in[0];
    const float* wgt  = (const float*)d_in[1];
    const float* bias = (const float*)d_in[2];
    float* out = (float*)d_out;

    dim3 grid(HH / R, 16, 1);   // (512, 16)
    dim3 block(256, 2, 1);      // 512 threads: y splits co
    conv3x3_kernel<<<grid, block, 0, stream>>>(x, wgt, bias, out);
}

// Round 5
// 351.019 us; speedup vs baseline: 3.1728x; 1.8076x over previous
//
#include <hip/hip_runtime.h>

// Conv2d NCHW, stride=1, pad=1, N=16, C=8, K=8, H=W=1024, 3x3, fp32.
// Round 5: v_pk_fma_f32. Scalar v_fma_f32 peaks at 78.6 TF (round 1 hit that
// roofline at 322us); packed fp32 doubles FMA throughput. Two output rows are
// packed per register pair; weights are pre-duplicated to {w,w} in d_ws so the
// packed weight operand is a single uniform s_load_dwordx2 (SGPR-pair source
// of VOP3P). Structure otherwise = round 1 (simple, allocator-friendly).

typedef __attribute__((ext_vector_type(2))) float f32x2;

#define HH 1024
#define WW 1024
#define CI 8
#define CO 8

// ---- prep: duplicate weights to {w,w} pairs in workspace ----
__global__ void dup_weights_kernel(const float* __restrict__ wgt,
                                   f32x2* __restrict__ dup) {
    const int i = threadIdx.x;          // 0..575
    if (i < CO * CI * 9) {
        const float w = wgt[i];
        f32x2 p; p.x = w; p.y = w;
        dup[i] = p;
    }
}

__global__ __launch_bounds__(256) void conv3x3_pk_kernel(
    const float* __restrict__ x,       // [16][8][1024][1024]
    const f32x2* __restrict__ wdup,    // [8][8][9] of {w,w}
    const float* __restrict__ bias,    // [8]
    float* __restrict__ out)           // [16][8][1024][1024]
{
    const int w  = blockIdx.x * 256 + threadIdx.x;  // 0..1023
    const int h0 = blockIdx.y * 2;                  // 0..1022 (rows h0, h0+1)
    const int n  = blockIdx.z;

    const long HW = (long)HH * WW;
    const float* xn = x + (long)n * CI * HW;

    // acc[co] = {row h0, row h0+1}
    f32x2 acc[CO];
#pragma unroll
    for (int co = 0; co < CO; ++co) {
        const float b = bias[co];                   // uniform -> s_load
        acc[co].x = b; acc[co].y = b;
    }

    for (int ci = 0; ci < CI; ++ci) {               // uniform runtime loop
        const float* xc = xn + (long)ci * HW;

        // Load 4 input rows (h0-1 .. h0+2) x 3 columns (w-1,w,w+1), zero-pad.
        float in[4][3];
#pragma unroll
        for (int r = 0; r < 4; ++r) {
            const int h = h0 - 1 + r;
            const bool hv = (h >= 0) && (h < HH);   // block-uniform
            const float* row = xc + (long)h * WW;
#pragma unroll
            for (int c = 0; c < 3; ++c) {
                const int wc = w - 1 + c;
                const bool v = hv && (wc >= 0) && (wc < WW);
                in[r][c] = v ? row[wc] : 0.0f;
            }
        }

        // Build row-pairs: pk[kh][c] = {in[kh][c], in[kh+1][c]}  (kh=0..2)
        f32x2 pk[3][3];
#pragma unroll
        for (int kh = 0; kh < 3; ++kh)
#pragma unroll
            for (int c = 0; c < 3; ++c) {
                pk[kh][c].x = in[kh][c];
                pk[kh][c].y = in[kh + 1][c];
            }

        // 8 co x 9 taps, each pk_fma covers both output rows.
#pragma unroll
        for (int co = 0; co < CO; ++co) {
            const f32x2* wp = wdup + ((co * CI + ci) * 9);
#pragma unroll
            for (int kh = 0; kh < 3; ++kh)
#pragma unroll
                for (int kw = 0; kw < 3; ++kw) {
                    const f32x2 w2 = wp[kh * 3 + kw];   // uniform -> s_load_dwordx2
                    asm("v_pk_fma_f32 %0, %1, %2, %0"
                        : "+v"(acc[co])
                        : "v"(pk[kh][kw]), "s"(w2));
                }
        }
    }

    // Stores: rows h0 and h0+1 for each co (coalesced along w).
#pragma unroll
    for (int co = 0; co < CO; ++co) {
        float* op = out + ((long)n * CO + co) * HW + (long)h0 * WW + w;
        op[0]  = acc[co].x;
        op[WW] = acc[co].y;
    }
}

extern "C" void kernel_launch(void* const* d_in, const int* in_sizes, int n_in,
                              void* d_out, int out_size, void* d_ws, size_t ws_size,
                              hipStream_t stream) {
    const float* x    = (const float*)d_in[0];
    const float* wgt  = (const float*)d_in[1];
    const float* bias = (const float*)d_in[2];
    float* out = (float*)d_out;
    f32x2* wdup = (f32x2*)d_ws;                 // 576 * 8B = 4608 B

    dup_weights_kernel<<<1, 576, 0, stream>>>(wgt, wdup);

    dim3 grid(WW / 256, HH / 2, 16);            // (4, 512, 16)
    dim3 block(256, 1, 1);
    conv3x3_pk_kernel<<<grid, block, 0, stream>>>(x, wdup, bias, out);
}

// Round 6
// 305.852 us; speedup vs baseline: 3.6413x; 1.1477x over previous
//
#include <hip/hip_runtime.h>

// Conv2d NCHW, stride=1, pad=1, N=16, C=8, K=8, H=W=1024, 3x3, fp32.
// Round 6: LDS-staged input tile. Round-1 analysis showed VALU time = 2.1x the
// pure-FMA floor (123us) -- the excess was per-lane predication + 64-bit
// per-lane address math + 3x redundant column loads. Here each ci stages
// 6 rows x 258 cols into LDS (coalesced, halo handled by 12 lanes, h-edge
// zero block-uniform); the 288 FMAs/ci read LDS via one vaddr + immediate
// offsets. Weights stay uniform->SGPR (round-1 proven). T14: next-ci loads
// issue into regs BEFORE compute, LDS write after; double-buffered; 1 sync/ci.

#define HH 1024
#define WW 1024
#define CI 8
#define CO 8
#define RT 4            // output rows per block
#define LW 258          // LDS row width: 256 + 2 halo cols

__global__ __launch_bounds__(256) void conv3x3_lds_kernel(
    const float* __restrict__ x,      // [16][8][1024][1024]
    const float* __restrict__ wgt,    // [8][8][3][3]
    const float* __restrict__ bias,   // [8]
    float* __restrict__ out)          // [16][8][1024][1024]
{
    __shared__ float lds[2][RT + 2][LW];

    const int tid = threadIdx.x;
    const int w0  = blockIdx.x * 256;          // block's first output col
    const int w   = w0 + tid;
    const int h0  = blockIdx.y * RT;
    const int n   = blockIdx.z;

    const long HW = (long)HH * WW;
    const float* xn = x + (long)n * CI * HW;

    // halo duty: lanes 0..5 -> left halo rows 0..5; lanes 6..11 -> right halo
    const bool halo  = (tid < 12);
    const int  hrow  = (tid < 6) ? tid : (tid - 6);
    const int  hcol  = (tid < 6) ? (w0 - 1) : (w0 + 256);
    const int  hlcol = (tid < 6) ? 0 : (LW - 1);
    const bool hcok  = (hcol >= 0) && (hcol < WW);

    float acc[CO][RT];
#pragma unroll
    for (int co = 0; co < CO; ++co) {
        const float b = bias[co];              // uniform -> s_load
#pragma unroll
        for (int r = 0; r < RT; ++r) acc[co][r] = b;
    }

    // ---- stage ci=0 ----
    {
        const float* xc = xn;                  // ci = 0
#pragma unroll
        for (int r = 0; r < RT + 2; ++r) {
            const int h = h0 - 1 + r;
            float v = 0.0f;
            if (h >= 0 && h < HH) v = xc[(long)h * WW + w];   // block-uniform guard
            lds[0][r][tid + 1] = v;
        }
        if (halo) {
            const int h = h0 - 1 + hrow;
            float v = 0.0f;
            if (hcok && h >= 0 && h < HH) v = xc[(long)h * WW + hcol];
            lds[0][hrow][hlcol] = v;
        }
    }
    __syncthreads();

    for (int ci = 0; ci < CI; ++ci) {          // uniform runtime loop
        const int buf = ci & 1;

        // ---- issue next-ci loads into regs (no wait) ----
        float ld[RT + 2];
        float ldh = 0.0f;
        if (ci < CI - 1) {
            const float* xc = xn + (long)(ci + 1) * HW;
#pragma unroll
            for (int r = 0; r < RT + 2; ++r) {
                const int h = h0 - 1 + r;
                float v = 0.0f;
                if (h >= 0 && h < HH) v = xc[(long)h * WW + w];
                ld[r] = v;
            }
            if (halo) {
                const int h = h0 - 1 + hrow;
                if (hcok && h >= 0 && h < HH) ldh = xc[(long)h * WW + hcol];
            }
        }

        // ---- compute on current buffer: 18 LDS reads, 288 FMAs ----
        const float* lp = &lds[buf][0][tid];   // col tid == w-1
        float in[RT + 2][3];
#pragma unroll
        for (int r = 0; r < RT + 2; ++r)
#pragma unroll
            for (int c = 0; c < 3; ++c)
                in[r][c] = lp[r * LW + c];     // ds_read, imm offsets

#pragma unroll
        for (int co = 0; co < CO; ++co) {
            const float* wp = wgt + ((co * CI + ci) * 9);
            float wv[9];
#pragma unroll
            for (int k = 0; k < 9; ++k) wv[k] = wp[k];   // uniform -> SGPR
#pragma unroll
            for (int r = 0; r < RT; ++r)
#pragma unroll
                for (int kh = 0; kh < 3; ++kh)
#pragma unroll
                    for (int kw = 0; kw < 3; ++kw)
                        acc[co][r] = fmaf(in[r + kh][kw], wv[kh * 3 + kw],
                                          acc[co][r]);
        }

        // ---- write staged regs to other buffer, then sync ----
        if (ci < CI - 1) {
            const int nb = buf ^ 1;
#pragma unroll
            for (int r = 0; r < RT + 2; ++r) lds[nb][r][tid + 1] = ld[r];
            if (halo) lds[nb][hrow][hlcol] = ldh;
        }
        __syncthreads();
    }

    // ---- stores: 8 co x 4 rows, coalesced along w ----
#pragma unroll
    for (int co = 0; co < CO; ++co) {
        float* op = out + ((long)n * CO + co) * HW + (long)h0 * WW + w;
#pragma unroll
        for (int r = 0; r < RT; ++r)
            op[(long)r * WW] = acc[co][r];
    }
}

extern "C" void kernel_launch(void* const* d_in, const int* in_sizes, int n_in,
                              void* d_out, int out_size, void* d_ws, size_t ws_size,
                              hipStream_t stream) {
    const float* x    = (const float*)d_in[0];
    const float* wgt  = (const float*)d_in[1];
    const float* bias = (const float*)d_in[2];
    float* out = (float*)d_out;

    dim3 grid(WW / 256, HH / RT, 16);   // (4, 256, 16)
    dim3 block(256, 1, 1);
    conv3x3_lds_kernel<<<grid, block, 0, stream>>>(x, wgt, bias, out);
}